// Round 1
// baseline (957.155 us; speedup 1.0000x reference)
//
#include <hip/hip_runtime.h>

#define BB 16
#define NN 256
#define DD 64
#define EE 64
#define HH 8

__device__ __forceinline__ void fma4(float* acc, float x, float4 w) {
    acc[0] += x * w.x; acc[1] += x * w.y; acc[2] += x * w.z; acc[3] += x * w.w;
}

// ---------------------------------------------------------------------------
// Kernel A: QKV projection.  Q/K/V laid out [b, h, n, d].
// grid 256 blocks (b x n-tile-of-16), 256 threads.
// ---------------------------------------------------------------------------
__global__ __launch_bounds__(256) void qkv_kernel(
    const float* __restrict__ query,
    const float* __restrict__ Wq, const float* __restrict__ bq,
    const float* __restrict__ Wk, const float* __restrict__ bk,
    const float* __restrict__ Wv, const float* __restrict__ bv,
    float* __restrict__ Q, float* __restrict__ K, float* __restrict__ V)
{
    // q_l[dd][r], padded to 20 so 16-float rows stay 16B-aligned (80B rows)
    __shared__ __align__(16) float q_l[64][20];
    const int b   = blockIdx.x >> 4;
    const int n0  = (blockIdx.x & 15) << 4;
    const int tid = threadIdx.x;

    for (int i = tid; i < 1024; i += 256) {
        const int r = i >> 6, dd = i & 63;
        q_l[dd][r] = query[(b * NN + n0 + r) * DD + dd];
    }
    __syncthreads();

    const float* Ws[3] = {Wq, Wk, Wv};
    const float* bs[3] = {bq, bk, bv};
    float*       Os[3] = {Q, K, V};

    for (int mtx = 0; mtx < 3; ++mtx) {
        const float* W = Ws[mtx];
        float*       O = Os[mtx];
        for (int half = 0; half < 2; ++half) {
            const int hd = tid + half * 256;
            const float bias = bs[mtx][hd];
            float acc[16];
            #pragma unroll
            for (int r = 0; r < 16; ++r) acc[r] = bias;
            for (int dd = 0; dd < 64; ++dd) {
                const float w = W[dd * 512 + hd];  // coalesced across lanes
                const float4 qa = *(const float4*)&q_l[dd][0];
                const float4 qb = *(const float4*)&q_l[dd][4];
                const float4 qc = *(const float4*)&q_l[dd][8];
                const float4 qd = *(const float4*)&q_l[dd][12];
                acc[0] += qa.x * w; acc[1] += qa.y * w; acc[2] += qa.z * w; acc[3] += qa.w * w;
                acc[4] += qb.x * w; acc[5] += qb.y * w; acc[6] += qb.z * w; acc[7] += qb.w * w;
                acc[8] += qc.x * w; acc[9] += qc.y * w; acc[10] += qc.z * w; acc[11] += qc.w * w;
                acc[12] += qd.x * w; acc[13] += qd.y * w; acc[14] += qd.z * w; acc[15] += qd.w * w;
            }
            const int h = hd >> 6, d = hd & 63;
            #pragma unroll
            for (int r = 0; r < 16; ++r)
                O[((b * HH + h) * NN + n0 + r) * DD + d] = acc[r];
        }
    }
}

// ---------------------------------------------------------------------------
// Kernel B: fused edges pass.
//   per (b, 4 n-rows) block, m chunked by 128:
//   bias = edges@Wa, gate = sigmoid(edges@Wg), score = QK^T/8 + bias
//   -> scores[b,h,n,m] (global), edges_out[b,m,n,e] = sum_h score*We,
//   -> Vg[b,h,n,d] = sum_m gate * V  (register-accumulated)
// grid 1024 blocks, 256 threads.
// ---------------------------------------------------------------------------
__global__ __launch_bounds__(256) void edges_kernel(
    const float* __restrict__ edges,
    const float* __restrict__ Wa, const float* __restrict__ ba,
    const float* __restrict__ Wg, const float* __restrict__ bg,
    const float* __restrict__ We, const float* __restrict__ be,
    const float* __restrict__ Q, const float* __restrict__ K, const float* __restrict__ V,
    float* __restrict__ scores, float* __restrict__ Vg, float* __restrict__ edges_out)
{
    __shared__ __align__(16) float wa_l[512];      // [e][h]
    __shared__ __align__(16) float wg_l[512];      // [e][h]
    __shared__ __align__(16) float we_l[512];      // [h][e]
    __shared__ float ba_l[8], bg_l[8], be_l[64];
    __shared__ __align__(16) float q_l[4][8][64];  // [n'][h][d]
    __shared__ __align__(16) float sc_l[4][128][8];// [n'][m'][h]
    __shared__ __align__(16) float g_l[4][128][8]; // [n'][m'][h]

    const int b    = blockIdx.x >> 6;
    const int n0   = (blockIdx.x & 63) << 2;
    const int tid  = threadIdx.x;
    const int lane = tid & 63;

    for (int i = tid; i < 512; i += 256) { wa_l[i] = Wa[i]; wg_l[i] = Wg[i]; we_l[i] = We[i]; }
    if (tid < 8)  { ba_l[tid] = ba[tid]; bg_l[tid] = bg[tid]; }
    if (tid < 64) be_l[tid] = be[tid];
    for (int i = tid; i < 2048; i += 256) {
        const int np = i >> 9, rem = i & 511, h = rem >> 6, d = rem & 63;
        q_l[np][h][d] = Q[((b * HH + h) * NN + n0 + np) * DD + d];
    }
    __syncthreads();

    // Vg accumulation mapping: thread -> (n'=tid>>6, h2=(tid>>4)&3, dq=tid&15)
    const int npv = tid >> 6;
    const int h2  = (tid >> 4) & 3;
    const int dq  = tid & 15;
    float vga[4] = {0.f, 0.f, 0.f, 0.f};
    float vgb[4] = {0.f, 0.f, 0.f, 0.f};

    // edges_out hoisted weights (per-lane e column of We, bias)
    float wecol[8];
    #pragma unroll
    for (int h = 0; h < 8; ++h) wecol[h] = we_l[h * 64 + lane];
    const float bev = be_l[lane];

    for (int m0 = 0; m0 < NN; m0 += 128) {
        // ---- phase 1: bias/gate/qk for elements (np, m0+mp) and (np, m0+mp+64)
        {
            const int np = tid >> 6;
            const int mp = lane;
            const float4* e0 = (const float4*)(edges +
                                (size_t)((b * NN + n0 + np) * NN + m0 + mp) * DD);
            const float4* e1 = e0 + 1024;  // +64 m rows

            float bias0[8], gate0[8], bias1[8], gate1[8];
            #pragma unroll
            for (int h = 0; h < 8; ++h) {
                bias0[h] = ba_l[h]; bias1[h] = ba_l[h];
                gate0[h] = bg_l[h]; gate1[h] = bg_l[h];
            }
            #pragma unroll 8
            for (int e4 = 0; e4 < 16; ++e4) {
                const float4 x0 = e0[e4];
                const float4 x1 = e1[e4];
                const float xs0[4] = {x0.x, x0.y, x0.z, x0.w};
                const float xs1[4] = {x1.x, x1.y, x1.z, x1.w};
                #pragma unroll
                for (int k = 0; k < 4; ++k) {
                    const int e = e4 * 4 + k;
                    const float4 wa0 = *(const float4*)&wa_l[e * 8];
                    const float4 wa1 = *(const float4*)&wa_l[e * 8 + 4];
                    const float4 wg0 = *(const float4*)&wg_l[e * 8];
                    const float4 wg1 = *(const float4*)&wg_l[e * 8 + 4];
                    const float a = xs0[k], c = xs1[k];
                    fma4(&bias0[0], a, wa0); fma4(&bias0[4], a, wa1);
                    fma4(&gate0[0], a, wg0); fma4(&gate0[4], a, wg1);
                    fma4(&bias1[0], c, wa0); fma4(&bias1[4], c, wa1);
                    fma4(&gate1[0], c, wg0); fma4(&gate1[4], c, wg1);
                }
            }
            float qk0[8], qk1[8];
            #pragma unroll
            for (int h = 0; h < 8; ++h) { qk0[h] = 0.f; qk1[h] = 0.f; }
            #pragma unroll
            for (int h = 0; h < 8; ++h) {
                const float4* kp0 = (const float4*)(K +
                                    (size_t)((b * HH + h) * NN + m0 + mp) * DD);
                const float4* kp1 = kp0 + 1024;  // +64 m rows
                const float4* qp  = (const float4*)&q_l[np][h][0];
                #pragma unroll 8
                for (int d4 = 0; d4 < 16; ++d4) {
                    const float4 q = qp[d4], ka = kp0[d4], kb = kp1[d4];
                    qk0[h] += q.x * ka.x + q.y * ka.y + q.z * ka.z + q.w * ka.w;
                    qk1[h] += q.x * kb.x + q.y * kb.y + q.z * kb.z + q.w * kb.w;
                }
            }
            float s0[8], s1[8], gg0[8], gg1[8];
            #pragma unroll
            for (int h = 0; h < 8; ++h) {
                s0[h]  = qk0[h] * 0.125f + bias0[h];
                s1[h]  = qk1[h] * 0.125f + bias1[h];
                gg0[h] = 1.f / (1.f + __expf(-gate0[h]));
                gg1[h] = 1.f / (1.f + __expf(-gate1[h]));
            }
            *(float4*)&sc_l[np][mp][0]      = make_float4(s0[0], s0[1], s0[2], s0[3]);
            *(float4*)&sc_l[np][mp][4]      = make_float4(s0[4], s0[5], s0[6], s0[7]);
            *(float4*)&sc_l[np][mp + 64][0] = make_float4(s1[0], s1[1], s1[2], s1[3]);
            *(float4*)&sc_l[np][mp + 64][4] = make_float4(s1[4], s1[5], s1[6], s1[7]);
            *(float4*)&g_l[np][mp][0]       = make_float4(gg0[0], gg0[1], gg0[2], gg0[3]);
            *(float4*)&g_l[np][mp][4]       = make_float4(gg0[4], gg0[5], gg0[6], gg0[7]);
            *(float4*)&g_l[np][mp + 64][0]  = make_float4(gg1[0], gg1[1], gg1[2], gg1[3]);
            *(float4*)&g_l[np][mp + 64][4]  = make_float4(gg1[4], gg1[5], gg1[6], gg1[7]);
        }
        __syncthreads();

        // ---- phase 2: scores -> global (coalesced along m)
        {
            const int rg = tid >> 6;
            #pragma unroll
            for (int rr = 0; rr < 8; ++rr) {
                const int r = rg * 8 + rr;
                const int np = r >> 3, h = r & 7;
                float* sp = scores + (size_t)((b * HH + h) * NN + n0 + np) * NN + m0;
                sp[lane]      = sc_l[np][lane][h];
                sp[64 + lane] = sc_l[np][64 + lane][h];
            }
        }

        // ---- phase 3: edges_out[b, m, n, e] = sum_h score * We[h,e] + be
        {
            const int w = tid >> 6;
            #pragma unroll 4
            for (int p = w * 128; p < w * 128 + 128; ++p) {
                const int mp = p >> 2, np = p & 3;
                const float4 sa = *(const float4*)&sc_l[np][mp][0];
                const float4 sb = *(const float4*)&sc_l[np][mp][4];
                const float v = bev
                    + sa.x * wecol[0] + sa.y * wecol[1] + sa.z * wecol[2] + sa.w * wecol[3]
                    + sb.x * wecol[4] + sb.y * wecol[5] + sb.z * wecol[6] + sb.w * wecol[7];
                edges_out[(size_t)((b * NN + m0 + mp) * NN + n0 + np) * DD + lane] = v;
            }
        }

        // ---- phase 4: Vg accumulate (register-resident across chunks)
        {
            const float* va = V + (size_t)((b * HH + h2)     * NN + m0) * DD + dq * 4;
            const float* vb = V + (size_t)((b * HH + h2 + 4) * NN + m0) * DD + dq * 4;
            #pragma unroll 8
            for (int mm = 0; mm < 128; ++mm) {
                const float ga = g_l[npv][mm][h2];
                const float gb = g_l[npv][mm][h2 + 4];
                const float4 v4a = *(const float4*)(va + mm * 64);
                const float4 v4b = *(const float4*)(vb + mm * 64);
                fma4(vga, ga, v4a);
                fma4(vgb, gb, v4b);
            }
        }
        __syncthreads();
    }

    *(float4*)(Vg + (size_t)((b * HH + h2)     * NN + n0 + npv) * DD + dq * 4) =
        make_float4(vga[0], vga[1], vga[2], vga[3]);
    *(float4*)(Vg + (size_t)((b * HH + h2 + 4) * NN + n0 + npv) * DD + dq * 4) =
        make_float4(vgb[0], vgb[1], vgb[2], vgb[3]);
}

// ---------------------------------------------------------------------------
// Kernel C: softmax(scores) @ Vg, then @ Wo + bo -> attention_output.
// grid 1024 blocks (b x n-tile-of-4), 512 threads (8 waves; wave = head).
// ---------------------------------------------------------------------------
__global__ __launch_bounds__(512) void out_kernel(
    const float* __restrict__ scores, const float* __restrict__ Vg,
    const float* __restrict__ Wo, const float* __restrict__ bo,
    float* __restrict__ att_out)
{
    __shared__ __align__(16) float s_l[4][8][256];
    __shared__ __align__(16) float o_l[4][512];
    __shared__ float red_l[2][4][64];
    const int b   = blockIdx.x >> 6;
    const int n0  = (blockIdx.x & 63) << 2;
    const int tid = threadIdx.x;

    for (int i = tid; i < 2048; i += 512) {
        const int np = i >> 9, rem = i & 511, h = rem >> 6, m4 = rem & 63;
        ((float4*)&s_l[np][h][0])[m4] =
            ((const float4*)(scores + (size_t)((b * HH + h) * NN + n0 + np) * NN))[m4];
    }
    __syncthreads();

    const int h = tid >> 6, lane = tid & 63;
    #pragma unroll
    for (int np = 0; np < 4; ++np) {
        const float v0 = s_l[np][h][lane],       v1 = s_l[np][h][lane + 64],
                    v2 = s_l[np][h][lane + 128], v3 = s_l[np][h][lane + 192];
        float mx = fmaxf(fmaxf(v0, v1), fmaxf(v2, v3));
        #pragma unroll
        for (int off = 32; off; off >>= 1) mx = fmaxf(mx, __shfl_xor(mx, off, 64));
        const float e0 = __expf(v0 - mx), e1 = __expf(v1 - mx),
                    e2 = __expf(v2 - mx), e3 = __expf(v3 - mx);
        float s = e0 + e1 + e2 + e3;
        #pragma unroll
        for (int off = 32; off; off >>= 1) s += __shfl_xor(s, off, 64);
        const float inv = 1.f / s;
        s_l[np][h][lane]       = e0 * inv; s_l[np][h][lane + 64]  = e1 * inv;
        s_l[np][h][lane + 128] = e2 * inv; s_l[np][h][lane + 192] = e3 * inv;
    }
    // rows are wave-private: no barrier needed before attn phase

    float acc[4] = {0.f, 0.f, 0.f, 0.f};
    const float* vgp = Vg + (size_t)((b * HH + h) * NN) * DD + lane;
    #pragma unroll 4
    for (int m4 = 0; m4 < 64; ++m4) {
        const float4 p0 = ((const float4*)&s_l[0][h][0])[m4];
        const float4 p1 = ((const float4*)&s_l[1][h][0])[m4];
        const float4 p2 = ((const float4*)&s_l[2][h][0])[m4];
        const float4 p3 = ((const float4*)&s_l[3][h][0])[m4];
        const float v0 = vgp[(m4 * 4 + 0) * 64], v1 = vgp[(m4 * 4 + 1) * 64],
                    v2 = vgp[(m4 * 4 + 2) * 64], v3 = vgp[(m4 * 4 + 3) * 64];
        acc[0] += p0.x * v0 + p0.y * v1 + p0.z * v2 + p0.w * v3;
        acc[1] += p1.x * v0 + p1.y * v1 + p1.z * v2 + p1.w * v3;
        acc[2] += p2.x * v0 + p2.y * v1 + p2.z * v2 + p2.w * v3;
        acc[3] += p3.x * v0 + p3.y * v1 + p3.z * v2 + p3.w * v3;
    }
    #pragma unroll
    for (int np = 0; np < 4; ++np) o_l[np][h * 64 + lane] = acc[np];
    __syncthreads();

    // projection: out[b,n,dd] = sum_hd o[n,hd] * Wo[hd,dd] + bo[dd], split 2-way over hd
    const int s_  = tid >> 8;
    const int rem = tid & 255;
    const int np  = rem >> 6, dd = rem & 63;
    float a = 0.f;
    const float* orow = &o_l[np][s_ * 256];
    const float* wp   = Wo + s_ * 256 * 64 + dd;
    #pragma unroll 4
    for (int k4 = 0; k4 < 64; ++k4) {
        const float4 o4 = ((const float4*)orow)[k4];
        a += o4.x * wp[(k4 * 4 + 0) * 64] + o4.y * wp[(k4 * 4 + 1) * 64]
           + o4.z * wp[(k4 * 4 + 2) * 64] + o4.w * wp[(k4 * 4 + 3) * 64];
    }
    red_l[s_][np][dd] = a;
    __syncthreads();
    if (s_ == 0)
        att_out[(b * NN + n0 + np) * DD + dd] = red_l[0][np][dd] + red_l[1][np][dd] + bo[dd];
}

extern "C" void kernel_launch(void* const* d_in, const int* in_sizes, int n_in,
                              void* d_out, int out_size, void* d_ws, size_t ws_size,
                              hipStream_t stream)
{
    const float* query = (const float*)d_in[0];
    const float* edges = (const float*)d_in[1];
    const float* Wq = (const float*)d_in[2];  const float* bq = (const float*)d_in[3];
    const float* Wk = (const float*)d_in[4];  const float* bk = (const float*)d_in[5];
    const float* Wv = (const float*)d_in[6];  const float* bv = (const float*)d_in[7];
    const float* Wa = (const float*)d_in[8];  const float* ba = (const float*)d_in[9];
    const float* Wg = (const float*)d_in[10]; const float* bg = (const float*)d_in[11];
    const float* Wo = (const float*)d_in[12]; const float* bo = (const float*)d_in[13];
    const float* We = (const float*)d_in[14]; const float* be = (const float*)d_in[15];

    float* att_out   = (float*)d_out;
    float* edges_out = (float*)d_out + 262144;  // B*N*D

    float* ws     = (float*)d_ws;
    float* Q      = ws;                // 2,097,152 floats
    float* K      = ws + 2097152;
    float* V      = ws + 4194304;
    float* Vg     = ws + 6291456;
    float* scores = ws + 8388608;      // 16,777,216 floats

    hipLaunchKernelGGL(qkv_kernel, dim3(256), dim3(256), 0, stream,
                       query, Wq, bq, Wk, bk, Wv, bv, Q, K, V);
    hipLaunchKernelGGL(edges_kernel, dim3(1024), dim3(256), 0, stream,
                       edges, Wa, ba, Wg, bg, We, be, Q, K, V, scores, Vg, edges_out);
    hipLaunchKernelGGL(out_kernel, dim3(1024), dim3(512), 0, stream,
                       scores, Vg, Wo, bo, att_out);
}

// Round 2
// 827.208 us; speedup vs baseline: 1.1571x; 1.1571x over previous
//
#include <hip/hip_runtime.h>

#define BB 16
#define NN 256
#define DD 64
#define EE 64
#define HH 8

__device__ __forceinline__ void fma4(float* acc, float x, float4 w) {
    acc[0] += x * w.x; acc[1] += x * w.y; acc[2] += x * w.z; acc[3] += x * w.w;
}

// ---------------------------------------------------------------------------
// Kernel 1: QKV projection. Q/K/V laid out [b, h, n, d].
// grid 512 (b x n-tile-of-8), 256 threads. LDS 2 KB.
// ---------------------------------------------------------------------------
__global__ __launch_bounds__(256) void qkv_kernel(
    const float* __restrict__ query,
    const float* __restrict__ Wq, const float* __restrict__ bq,
    const float* __restrict__ Wk, const float* __restrict__ bk,
    const float* __restrict__ Wv, const float* __restrict__ bv,
    float* __restrict__ Q, float* __restrict__ K, float* __restrict__ V)
{
    __shared__ __align__(16) float q_l[8][64];
    const int b   = blockIdx.x >> 5;
    const int n0  = (blockIdx.x & 31) << 3;
    const int tid = threadIdx.x;

    if (tid < 128)
        ((float4*)&q_l[0][0])[tid] =
            ((const float4*)(query + (size_t)(b * NN + n0) * DD))[tid];
    __syncthreads();

    const int w    = tid >> 6;       // wave -> rows 2w, 2w+1
    const int lane = tid & 63;
    const int r0   = w * 2;
    const float* Ws[3] = {Wq, Wk, Wv};
    const float* bs[3] = {bq, bk, bv};
    float*       Os[3] = {Q, K, V};

    for (int mtx = 0; mtx < 3; ++mtx) {
        const float* W = Ws[mtx];
        float acc[2][8];
        #pragma unroll
        for (int j = 0; j < 8; ++j) {
            const float bb = bs[mtx][j * 64 + lane];
            acc[0][j] = bb; acc[1][j] = bb;
        }
        for (int d4 = 0; d4 < 16; ++d4) {
            const float4 qa = ((const float4*)&q_l[r0][0])[d4];
            const float4 qb = ((const float4*)&q_l[r0 + 1][0])[d4];
            #pragma unroll
            for (int j = 0; j < 8; ++j) {
                const int col = j * 64 + lane;
                const float w0 = W[(d4 * 4 + 0) * 512 + col];
                const float w1 = W[(d4 * 4 + 1) * 512 + col];
                const float w2 = W[(d4 * 4 + 2) * 512 + col];
                const float w3 = W[(d4 * 4 + 3) * 512 + col];
                acc[0][j] += qa.x * w0 + qa.y * w1 + qa.z * w2 + qa.w * w3;
                acc[1][j] += qb.x * w0 + qb.y * w1 + qb.z * w2 + qb.w * w3;
            }
        }
        #pragma unroll
        for (int j = 0; j < 8; ++j) {
            float* op = Os[mtx] + (size_t)((b * HH + j) * NN + n0) * DD + lane;
            op[(r0)     * DD] = acc[0][j];
            op[(r0 + 1) * DD] = acc[1][j];
        }
    }
}

// ---------------------------------------------------------------------------
// Kernel 2: fused edges pass (no m-loop carry; gates materialized).
//   block = (b, 4 n-rows, 64 m-cols); thread (np, mp) owns one (n,m) pair.
//   bias = edges@Wa, gate = sigmoid(edges@Wg), score = QK^T/8 + bias
//   -> scores[b,h,n,m], gates[b,h,n,m], edges_out[b,m,n,e]
// grid 4096, 256 threads. LDS ~20.5 KB -> ~3 blocks/CU.
// ---------------------------------------------------------------------------
__global__ __launch_bounds__(256) void edges_kernel(
    const float* __restrict__ edges,
    const float* __restrict__ Wa, const float* __restrict__ ba,
    const float* __restrict__ Wg, const float* __restrict__ bg,
    const float* __restrict__ We, const float* __restrict__ be,
    const float* __restrict__ Q, const float* __restrict__ K,
    float* __restrict__ scores, float* __restrict__ gates,
    float* __restrict__ edges_out)
{
    __shared__ __align__(16) float wa_l[EE * HH];   // [e][h]  2 KB
    __shared__ __align__(16) float wg_l[EE * HH];   // [e][h]  2 KB
    __shared__ float ba_l[HH], bg_l[HH];
    __shared__ __align__(16) float q_l[4][HH][DD];  // 8 KB
    __shared__ __align__(16) float sc_l[4][64][HH]; // 8 KB

    const int mt   = blockIdx.x & 3;
    const int nt   = (blockIdx.x >> 2) & 63;
    const int b    = blockIdx.x >> 8;
    const int n0   = nt << 2;
    const int m0   = mt << 6;
    const int tid  = threadIdx.x;
    const int lane = tid & 63;
    const int np   = tid >> 6;

    for (int i = tid; i < 512; i += 256) { wa_l[i] = Wa[i]; wg_l[i] = Wg[i]; }
    if (tid < 8) { ba_l[tid] = ba[tid]; bg_l[tid] = bg[tid]; }
    for (int j = tid; j < 512; j += 256) {
        const int qnp = j >> 7, rem = j & 127, h = rem >> 4, dq = rem & 15;
        ((float4*)&q_l[qnp][h][0])[dq] =
            ((const float4*)(Q + (size_t)((b * HH + h) * NN + n0 + qnp) * DD))[dq];
    }
    float wecol[8];
    #pragma unroll
    for (int h = 0; h < 8; ++h) wecol[h] = We[h * EE + lane];
    const float bev = be[lane];
    __syncthreads();

    const int mp = lane;
    // ---- phase 1: bias / gate / qk for (n0+np, m0+mp)
    float bias[8], gate[8];
    #pragma unroll
    for (int h = 0; h < 8; ++h) { bias[h] = ba_l[h]; gate[h] = bg_l[h]; }
    const float4* ep = (const float4*)(edges +
                        (size_t)((b * NN + n0 + np) * NN + m0 + mp) * DD);
    #pragma unroll 4
    for (int e4 = 0; e4 < 16; ++e4) {
        const float4 x = ep[e4];
        const float xs[4] = {x.x, x.y, x.z, x.w};
        #pragma unroll
        for (int k = 0; k < 4; ++k) {
            const int e = e4 * 4 + k;
            const float4 wa0 = *(const float4*)&wa_l[e * 8];
            const float4 wa1 = *(const float4*)&wa_l[e * 8 + 4];
            const float4 wg0 = *(const float4*)&wg_l[e * 8];
            const float4 wg1 = *(const float4*)&wg_l[e * 8 + 4];
            fma4(&bias[0], xs[k], wa0); fma4(&bias[4], xs[k], wa1);
            fma4(&gate[0], xs[k], wg0); fma4(&gate[4], xs[k], wg1);
        }
    }
    float qk[8];
    #pragma unroll
    for (int h = 0; h < 8; ++h) {
        const float4* kp = (const float4*)(K + (size_t)((b * HH + h) * NN + m0 + mp) * DD);
        const float4* qp = (const float4*)&q_l[np][h][0];
        float s = 0.f;
        #pragma unroll 8
        for (int d4 = 0; d4 < 16; ++d4) {
            const float4 kk = kp[d4], qq = qp[d4];
            s += qq.x * kk.x + qq.y * kk.y + qq.z * kk.z + qq.w * kk.w;
        }
        qk[h] = s;
    }
    float sc[8], gg[8];
    #pragma unroll
    for (int h = 0; h < 8; ++h) {
        sc[h] = qk[h] * 0.125f + bias[h];
        gg[h] = 1.f / (1.f + __expf(-gate[h]));
    }
    #pragma unroll
    for (int h = 0; h < 8; ++h) {
        const size_t off = (size_t)((b * HH + h) * NN + n0 + np) * NN + m0 + mp;
        scores[off] = sc[h];
        gates[off]  = gg[h];
    }
    *(float4*)&sc_l[np][mp][0] = make_float4(sc[0], sc[1], sc[2], sc[3]);
    *(float4*)&sc_l[np][mp][4] = make_float4(sc[4], sc[5], sc[6], sc[7]);
    __syncthreads();

    // ---- phase 2: edges_out[b, m, n, e] = sum_h score * We[h,e] + be
    #pragma unroll 8
    for (int pi = 0; pi < 64; ++pi) {
        const int p   = np * 64 + pi;
        const int mp2 = p >> 2, np2 = p & 3;
        const float4 sa = *(const float4*)&sc_l[np2][mp2][0];
        const float4 sb = *(const float4*)&sc_l[np2][mp2][4];
        const float v = bev
            + sa.x * wecol[0] + sa.y * wecol[1] + sa.z * wecol[2] + sa.w * wecol[3]
            + sb.x * wecol[4] + sb.y * wecol[5] + sb.z * wecol[6] + sb.w * wecol[7];
        edges_out[(size_t)((b * NN + m0 + mp2) * NN + n0 + np2) * DD + lane] = v;
    }
}

// ---------------------------------------------------------------------------
// Kernel 3: Vg[b,h,n,d] = sum_m gates[b,h,n,m] * V[b,h,m,d]
// grid 2048 (b*h x n-tile-of-16), 256 threads. LDS 16 KB.
// ---------------------------------------------------------------------------
__global__ __launch_bounds__(256) void vg_kernel(
    const float* __restrict__ gates, const float* __restrict__ V,
    float* __restrict__ Vg)
{
    __shared__ __align__(16) float g_l[16][256];
    const int bh  = blockIdx.x >> 4;
    const int n0  = (blockIdx.x & 15) << 4;
    const int tid = threadIdx.x;

    const float4* gsrc = (const float4*)(gates + (size_t)bh * NN * NN + (size_t)n0 * NN);
    #pragma unroll
    for (int i = 0; i < 4; ++i)
        ((float4*)&g_l[0][0])[tid + i * 256] = gsrc[tid + i * 256];
    __syncthreads();

    const int wv   = tid >> 6;
    const int msub = (tid >> 4) & 3;
    const int dq   = tid & 15;
    float acc[4][4] = {};
    const float* vb = V + (size_t)bh * NN * DD + dq * 4;
    for (int mq = 0; mq < 64; ++mq) {
        const int m = mq * 4 + msub;
        const float4 v4 = *(const float4*)(vb + m * DD);
        #pragma unroll
        for (int i = 0; i < 4; ++i) {
            const float a = g_l[wv * 4 + i][m];
            acc[i][0] += a * v4.x; acc[i][1] += a * v4.y;
            acc[i][2] += a * v4.z; acc[i][3] += a * v4.w;
        }
    }
    #pragma unroll
    for (int i = 0; i < 4; ++i) {
        #pragma unroll
        for (int c = 0; c < 4; ++c) {
            acc[i][c] += __shfl_xor(acc[i][c], 16, 64);
            acc[i][c] += __shfl_xor(acc[i][c], 32, 64);
        }
        if (msub == 0)
            *(float4*)(Vg + (size_t)(bh * NN + n0 + wv * 4 + i) * DD + dq * 4) =
                make_float4(acc[i][0], acc[i][1], acc[i][2], acc[i][3]);
    }
}

// ---------------------------------------------------------------------------
// Kernel 4: softmax(scores) @ Vg, then @ Wo + bo -> attention_output.
// grid 512 (b x n-tile-of-8), 512 threads (wave = n-row). LDS 24 KB.
// Per-h streaming so the whole block shares each Vg slice through L1.
// ---------------------------------------------------------------------------
__global__ __launch_bounds__(512) void out_kernel(
    const float* __restrict__ scores, const float* __restrict__ Vg,
    const float* __restrict__ Wo, const float* __restrict__ bo,
    float* __restrict__ att_out)
{
    __shared__ __align__(16) float att_l[8][256];
    __shared__ __align__(16) float o_l[8][512];
    const int b    = blockIdx.x >> 5;
    const int n0   = (blockIdx.x & 31) << 3;
    const int tid  = threadIdx.x;
    const int np   = tid >> 6;       // wave = row
    const int lane = tid & 63;
    const int msub = (tid >> 4) & 3;
    const int dq   = tid & 15;

    for (int h = 0; h < 8; ++h) {
        const float* sp = scores + (size_t)((b * HH + h) * NN + n0 + np) * NN;
        const float4 s4 = ((const float4*)sp)[lane];
        float mx = fmaxf(fmaxf(s4.x, s4.y), fmaxf(s4.z, s4.w));
        #pragma unroll
        for (int off = 32; off; off >>= 1) mx = fmaxf(mx, __shfl_xor(mx, off, 64));
        const float e0 = __expf(s4.x - mx), e1 = __expf(s4.y - mx),
                    e2 = __expf(s4.z - mx), e3 = __expf(s4.w - mx);
        float sm = e0 + e1 + e2 + e3;
        #pragma unroll
        for (int off = 32; off; off >>= 1) sm += __shfl_xor(sm, off, 64);
        const float inv = 1.f / sm;
        ((float4*)&att_l[np][0])[lane] = make_float4(e0 * inv, e1 * inv, e2 * inv, e3 * inv);
        // att_l row is wave-private: no barrier needed before reading it

        float a0 = 0.f, a1 = 0.f, a2 = 0.f, a3 = 0.f;
        const float* vb = Vg + (size_t)((b * HH + h) * NN) * DD + dq * 4;
        for (int mq = 0; mq < 64; ++mq) {
            const int m = mq * 4 + msub;
            const float a = att_l[np][m];
            const float4 v4 = *(const float4*)(vb + m * DD);
            a0 += a * v4.x; a1 += a * v4.y; a2 += a * v4.z; a3 += a * v4.w;
        }
        a0 += __shfl_xor(a0, 16, 64); a0 += __shfl_xor(a0, 32, 64);
        a1 += __shfl_xor(a1, 16, 64); a1 += __shfl_xor(a1, 32, 64);
        a2 += __shfl_xor(a2, 16, 64); a2 += __shfl_xor(a2, 32, 64);
        a3 += __shfl_xor(a3, 16, 64); a3 += __shfl_xor(a3, 32, 64);
        if (msub == 0)
            *(float4*)&o_l[np][h * 64 + dq * 4] = make_float4(a0, a1, a2, a3);
        __syncthreads();   // keep waves in lockstep for L1 reuse of Vg slices
    }

    // projection: wave np reads its own o_l row (wave-private)
    float acc = bo[lane];
    const float*  wp   = Wo + lane;
    const float4* orow = (const float4*)&o_l[np][0];
    #pragma unroll 4
    for (int k4 = 0; k4 < 128; ++k4) {
        const float4 o4 = orow[k4];
        acc += o4.x * wp[(k4 * 4 + 0) * 64] + o4.y * wp[(k4 * 4 + 1) * 64]
             + o4.z * wp[(k4 * 4 + 2) * 64] + o4.w * wp[(k4 * 4 + 3) * 64];
    }
    att_out[(size_t)(b * NN + n0 + np) * DD + lane] = acc;
}

extern "C" void kernel_launch(void* const* d_in, const int* in_sizes, int n_in,
                              void* d_out, int out_size, void* d_ws, size_t ws_size,
                              hipStream_t stream)
{
    const float* query = (const float*)d_in[0];
    const float* edges = (const float*)d_in[1];
    const float* Wq = (const float*)d_in[2];  const float* bq = (const float*)d_in[3];
    const float* Wk = (const float*)d_in[4];  const float* bk = (const float*)d_in[5];
    const float* Wv = (const float*)d_in[6];  const float* bv = (const float*)d_in[7];
    const float* Wa = (const float*)d_in[8];  const float* ba = (const float*)d_in[9];
    const float* Wg = (const float*)d_in[10]; const float* bg = (const float*)d_in[11];
    const float* Wo = (const float*)d_in[12]; const float* bo = (const float*)d_in[13];
    const float* We = (const float*)d_in[14]; const float* be = (const float*)d_in[15];

    float* att_out   = (float*)d_out;
    float* edges_out = (float*)d_out + 262144;  // B*N*D

    float* ws     = (float*)d_ws;
    float* Q      = ws;                 // 2,097,152 floats
    float* K      = ws + 2097152;
    float* V      = ws + 4194304;
    float* Vg     = ws + 6291456;
    float* gates  = ws + 8388608;       // 8,388,608 floats
    float* scores = ws + 16777216;      // 8,388,608 floats

    hipLaunchKernelGGL(qkv_kernel, dim3(512), dim3(256), 0, stream,
                       query, Wq, bq, Wk, bk, Wv, bv, Q, K, V);
    hipLaunchKernelGGL(edges_kernel, dim3(4096), dim3(256), 0, stream,
                       edges, Wa, ba, Wg, bg, We, be, Q, K, scores, gates, edges_out);
    hipLaunchKernelGGL(vg_kernel, dim3(2048), dim3(256), 0, stream,
                       gates, V, Vg);
    hipLaunchKernelGGL(out_kernel, dim3(512), dim3(512), 0, stream,
                       scores, Vg, Wo, bo, att_out);
}